// Round 1
// baseline (866.126 us; speedup 1.0000x reference)
//
#include <hip/hip_runtime.h>

// LinearAttention restructured:
//   kv = W_kv^T @ x                      (K1, 34.4 GF)
//   k  = softmax_L(k)                    (K2)
//   ctxT[b,h][e][d] = sum_n k[d,n]v[e,n] (K3, 4.3 GF, n-split + atomics)
//   A2T[b][g=(h,d)][c] = sum_e ctx[d,e] w_out[(h,e),c]   (K4a, 0.5 GF)
//   MT[b][c'][c] = SCALE * sum_g wqT[g][c'] A2T[b][g][c] (K4m, 2.1 GF)
//   out[b] = MT[b]^T-applied:  out[c,l] = sum_c' MT[c'][c]... wait no:
//   out[b][c][l] = sum_c' MT_as_A[k=c'][m=c] x[c'][l] + b_out[c]  (K5, 17.2 GF)
// q is never materialized: it is linear in x, folded into M.
// All fp32 this round (correctness baseline; bf16/MFMA conversion later
// once absmax headroom vs the 9.88e-3 threshold is known).

#define Bb_ 8
#define Cc_ 512
#define Ll_ 4096
#define Hh_ 8
#define Dd_ 64
#define SCALE_ 0.125f

// ---------------- generic 128x128x8-tile fp32 GEMM -------------------------
// C[m][n] (+bias[m]) = sum_k A[k][m] * B[k][n]
// grid: (N/128, M/128, batch). M,N multiples of 128; K multiple of 8.
__global__ __launch_bounds__(256)
void gemm128(const float* __restrict__ A, int lda, long aStride,
             const float* __restrict__ B, int ldb, long bStride,
             float* __restrict__ C, int ldc, long cStride,
             int K, const float* __restrict__ bias)
{
    __shared__ float As[8][128];
    __shared__ float Bs[8][128];
    const int tid = threadIdx.x;
    const int tx = tid & 15;        // n-dir, 8 cols each
    const int ty = tid >> 4;        // m-dir, 8 rows each
    const int m0 = blockIdx.y << 7;
    const int n0 = blockIdx.x << 7;
    const float* Ab = A + (long)blockIdx.z * aStride + m0;
    const float* Bb = B + (long)blockIdx.z * bStride + n0;
    float* Cb = C + (long)blockIdx.z * cStride;

    const int lk = tid >> 5;           // 0..7 (k-row of tile)
    const int lm = (tid & 31) << 2;    // 0..124 (col*4)

    float acc[8][8] = {};

    for (int k0 = 0; k0 < K; k0 += 8) {
        const float4 av = *(const float4*)(Ab + (long)(k0 + lk) * lda + lm);
        const float4 bv = *(const float4*)(Bb + (long)(k0 + lk) * ldb + lm);
        __syncthreads();               // protect previous tile's compute
        *(float4*)&As[lk][lm] = av;
        *(float4*)&Bs[lk][lm] = bv;
        __syncthreads();
#pragma unroll
        for (int kk = 0; kk < 8; ++kk) {
            float a[8], b[8];
            *(float4*)(a)     = *(const float4*)&As[kk][ty * 8];
            *(float4*)(a + 4) = *(const float4*)&As[kk][ty * 8 + 4];
            *(float4*)(b)     = *(const float4*)&Bs[kk][tx * 8];
            *(float4*)(b + 4) = *(const float4*)&Bs[kk][tx * 8 + 4];
#pragma unroll
            for (int i = 0; i < 8; ++i)
#pragma unroll
                for (int j = 0; j < 8; ++j)
                    acc[i][j] = fmaf(a[i], b[j], acc[i][j]);
        }
    }

#pragma unroll
    for (int i = 0; i < 8; ++i) {
        const int m = m0 + ty * 8 + i;
        const float bi = bias ? bias[m] : 0.0f;
        float4 o0, o1;
        o0.x = acc[i][0] + bi; o0.y = acc[i][1] + bi;
        o0.z = acc[i][2] + bi; o0.w = acc[i][3] + bi;
        o1.x = acc[i][4] + bi; o1.y = acc[i][5] + bi;
        o1.z = acc[i][6] + bi; o1.w = acc[i][7] + bi;
        *(float4*)(Cb + (long)m * ldc + n0 + tx * 8)     = o0;
        *(float4*)(Cb + (long)m * ldc + n0 + tx * 8 + 4) = o1;
    }
}

// ---------------- softmax over L per (b, f<512) row, in place --------------
__global__ __launch_bounds__(256)
void softmax_rows(float* __restrict__ kv)
{
    const int row = blockIdx.x;            // 0..4095
    const int b = row >> 9, f = row & 511;
    float* p = kv + (long)b * (1024L * 4096) + (long)f * 4096;
    const int tid = threadIdx.x;

    float v[16];
#pragma unroll
    for (int i = 0; i < 4; ++i)
        *(float4*)(v + 4 * i) = *(const float4*)(p + (tid + i * 256) * 4);

    float mx = -3.4e38f;
#pragma unroll
    for (int i = 0; i < 16; ++i) mx = fmaxf(mx, v[i]);
#pragma unroll
    for (int off = 32; off > 0; off >>= 1)
        mx = fmaxf(mx, __shfl_down(mx, off));

    __shared__ float red[8];
    if ((tid & 63) == 0) red[tid >> 6] = mx;
    __syncthreads();
    mx = fmaxf(fmaxf(red[0], red[1]), fmaxf(red[2], red[3]));

    float s = 0.0f;
#pragma unroll
    for (int i = 0; i < 16; ++i) { v[i] = __expf(v[i] - mx); s += v[i]; }
#pragma unroll
    for (int off = 32; off > 0; off >>= 1)
        s += __shfl_down(s, off);
    if ((tid & 63) == 0) red[4 + (tid >> 6)] = s;
    __syncthreads();
    const float inv = 1.0f / (red[4] + red[5] + red[6] + red[7]);

#pragma unroll
    for (int i = 0; i < 16; ++i) v[i] *= inv;
#pragma unroll
    for (int i = 0; i < 4; ++i)
        *(float4*)(p + (tid + i * 256) * 4) = *(const float4*)(v + 4 * i);
}

// ---------------- context: ctxT[bh][e*64+d] += sum_n k[d,n] v[e,n] ---------
#define NSPLIT 16
__global__ __launch_bounds__(256)
void context_kernel(const float* __restrict__ kv, float* __restrict__ ctxT)
{
    const int bh = blockIdx.x;             // b*8+h
    const int b = bh >> 3, h = bh & 7;
    const float* kbase = kv + (long)b * (1024L * 4096) + (long)(h * 64) * 4096;
    const float* vbase = kv + (long)b * (1024L * 4096) + (long)(512 + h * 64) * 4096;
    const int n0 = blockIdx.y * (4096 / NSPLIT);   // 256-wide n slab

    __shared__ float ks[64][65];
    __shared__ float vs[64][65];
    const int tid = threadIdx.x;
    const int tx = tid & 15, ty = tid >> 4;
    const int lr = tid >> 4;            // load row base
    const int lc = (tid & 15) * 4;      // load col*4

    float acc[4][4] = {};

    for (int nc = 0; nc < 4096 / NSPLIT; nc += 64) {
        __syncthreads();
#pragma unroll
        for (int i = 0; i < 4; ++i) {
            const int r = lr + 16 * i;
            const float4 kq = *(const float4*)(kbase + (long)r * 4096 + n0 + nc + lc);
            const float4 vq = *(const float4*)(vbase + (long)r * 4096 + n0 + nc + lc);
            ks[r][lc] = kq.x; ks[r][lc + 1] = kq.y; ks[r][lc + 2] = kq.z; ks[r][lc + 3] = kq.w;
            vs[r][lc] = vq.x; vs[r][lc + 1] = vq.y; vs[r][lc + 2] = vq.z; vs[r][lc + 3] = vq.w;
        }
        __syncthreads();
#pragma unroll 4
        for (int n = 0; n < 64; ++n) {
            float a[4], bv[4];
#pragma unroll
            for (int i = 0; i < 4; ++i) a[i] = ks[ty * 4 + i][n];
#pragma unroll
            for (int j = 0; j < 4; ++j) bv[j] = vs[tx * 4 + j][n];
#pragma unroll
            for (int i = 0; i < 4; ++i)
#pragma unroll
                for (int j = 0; j < 4; ++j)
                    acc[i][j] = fmaf(a[i], bv[j], acc[i][j]);
        }
    }

    float* base = ctxT + (long)bh * 4096;
#pragma unroll
    for (int i = 0; i < 4; ++i)
#pragma unroll
        for (int j = 0; j < 4; ++j)
            atomicAdd(base + (tx * 4 + j) * 64 + (ty * 4 + i), acc[i][j]);
}

// ---------- A2T[b][(h*64+d)*512+c] = sum_e ctxT[e][d] * w_out[(h,e),c] -----
__global__ __launch_bounds__(256)
void a2t_kernel(const float* __restrict__ ctxT, const float* __restrict__ w_out,
                float* __restrict__ a2t)
{
    const int ct = blockIdx.x, h = blockIdx.y, b = blockIdx.z;
    __shared__ float cs[64][64];      // cs[e][d]
    __shared__ float wsh[64][128];    // wsh[e][c]
    const int tid = threadIdx.x;
    const float* cbase = ctxT + (long)(b * 8 + h) * 4096;
    {
        const int lr = tid >> 4, lc4 = (tid & 15) * 4;
#pragma unroll
        for (int i = 0; i < 4; ++i) {
            const int e = lr + 16 * i;
            *(float4*)&cs[e][lc4] = *(const float4*)(cbase + e * 64 + lc4);
        }
        const float* wbase = w_out + (long)(h * 64) * 512 + ct * 128;
        const int wr = tid >> 5, wc4 = (tid & 31) * 4;
#pragma unroll
        for (int i = 0; i < 8; ++i) {
            const int e = wr + 8 * i;
            *(float4*)&wsh[e][wc4] = *(const float4*)(wbase + (long)e * 512 + wc4);
        }
    }
    __syncthreads();
    const int tx = tid & 15, ty = tid >> 4;   // n: tx*8, m(d): ty*4
    float acc[4][8] = {};
    for (int e = 0; e < 64; ++e) {
        float a[4], bv[8];
#pragma unroll
        for (int i = 0; i < 4; ++i) a[i] = cs[e][ty * 4 + i];
#pragma unroll
        for (int j = 0; j < 8; ++j) bv[j] = wsh[e][tx * 8 + j];
#pragma unroll
        for (int i = 0; i < 4; ++i)
#pragma unroll
            for (int j = 0; j < 8; ++j)
                acc[i][j] = fmaf(a[i], bv[j], acc[i][j]);
    }
    float* obase = a2t + (long)b * 262144 + (long)(h * 64) * 512 + ct * 128;
#pragma unroll
    for (int i = 0; i < 4; ++i) {
        float4 o0, o1;
        o0.x = acc[i][0]; o0.y = acc[i][1]; o0.z = acc[i][2]; o0.w = acc[i][3];
        o1.x = acc[i][4]; o1.y = acc[i][5]; o1.z = acc[i][6]; o1.w = acc[i][7];
        *(float4*)(obase + (long)(ty * 4 + i) * 512 + tx * 8)     = o0;
        *(float4*)(obase + (long)(ty * 4 + i) * 512 + tx * 8 + 4) = o1;
    }
}

// ---------------- wqT[g][c] = SCALE * w_qkv[c*1536 + g], g,c < 512 ---------
__global__ __launch_bounds__(256)
void transpose_wq(const float* __restrict__ w_qkv, float* __restrict__ wqT)
{
    __shared__ float t[32][33];
    const int g0 = blockIdx.x * 32, c0 = blockIdx.y * 32;
    const int lx = threadIdx.x & 31, ly = threadIdx.x >> 5;  // 32x8
#pragma unroll
    for (int i = 0; i < 4; ++i) {
        const int c = c0 + ly + 8 * i;
        t[ly + 8 * i][lx] = w_qkv[(long)c * 1536 + g0 + lx];
    }
    __syncthreads();
#pragma unroll
    for (int i = 0; i < 4; ++i) {
        const int g = g0 + ly + 8 * i;
        wqT[(long)g * 512 + c0 + lx] = SCALE_ * t[lx][ly + 8 * i];
    }
}

extern "C" void kernel_launch(void* const* d_in, const int* in_sizes, int n_in,
                              void* d_out, int out_size, void* d_ws, size_t ws_size,
                              hipStream_t stream)
{
    const float* x      = (const float*)d_in[0];   // (8,512,4096)
    const float* w_qkv  = (const float*)d_in[1];   // (512,1536)
    const float* w_out  = (const float*)d_in[2];   // (512,512)
    const float* b_out  = (const float*)d_in[3];   // (512,)
    float* out = (float*)d_out;                    // (8,512,4096)
    float* ws  = (float*)d_ws;

    // workspace layout (floats): needs ~146 MB
    float* kv   = ws;                    // 8*1024*4096 = 33554432
    float* ctxT = ws + 33554432;         // 64*4096     = 262144
    float* a2t  = ws + 33816576;         // 8*512*512   = 2097152
    float* mt   = ws + 35913728;         // 8*512*512   = 2097152
    float* wqT  = ws + 38010880;         // 512*512     = 262144

    // K0: scaled transpose of the q-columns of w_qkv
    transpose_wq<<<dim3(16, 16), 256, 0, stream>>>(w_qkv, wqT);

    // K1: kv[b][f][l] = sum_c w_qkv[c][512+f] * x[b][c][l]   (f < 1024)
    gemm128<<<dim3(32, 8, 8), 256, 0, stream>>>(
        w_qkv + 512, 1536, 0L,  x, 4096, 2097152L,
        kv, 4096, 4194304L, 512, nullptr);

    // K2: softmax over L on the k half (f < 512), in place
    softmax_rows<<<4096, 256, 0, stream>>>(kv);

    // K3: ctxT (zero first; ws is poisoned each call)
    hipMemsetAsync(ctxT, 0, 262144 * sizeof(float), stream);
    context_kernel<<<dim3(64, NSPLIT), 256, 0, stream>>>(kv, ctxT);

    // K4a: A2T
    a2t_kernel<<<dim3(4, 8, 8), 256, 0, stream>>>(ctxT, w_out, a2t);

    // K4m: MT[b][c'][c] = sum_g wqT[g][c'] * a2t[b][g][c]
    gemm128<<<dim3(4, 4, 8), 256, 0, stream>>>(
        wqT, 512, 0L,  a2t, 512, 262144L,
        mt, 512, 262144L, 512, nullptr);

    // K5: out[b][c][l] = sum_c' mt[b][c'][c] * x[b][c'][l] + b_out[c]
    gemm128<<<dim3(32, 4, 8), 256, 0, stream>>>(
        mt, 512, 262144L,  x, 4096, 2097152L,
        out, 4096, 2097152L, 512, b_out);
}

// Round 2
// 338.526 us; speedup vs baseline: 2.5585x; 2.5585x over previous
//
#include <hip/hip_runtime.h>

// LinearAttention, fp16-MFMA restructuring (round 2).
//   xT   = transpose+cvt(x)          [b][l][c] f16   (B-operand for K1,K5)
//   kv   = wkvT @ xT^T  (MFMA)       [b][f][l] f16, f<512:k, f>=512:v
//   k    = softmax_L(k)              in place, f16
//   ctxT = k v^T  (fp32 VALU, n-split atomics)  [bh][e*64+d] f32
//   a2tT = (ctx . w_out)^T           [b][c][g] f16  (n..k-fast for M-build)
//   Mf   = a2tT @ wqs^T (MFMA)       [b][c][c'] f16 = A-operand of K5
//   out  = Mf @ xT^T + b_out (MFMA, fp32 out)
// q never materialized (linear in x, folded into Mf).
// fp16 chosen over bf16: 2^-11 rounding keeps predicted absmax ~3e-3 vs
// threshold 9.9e-3; bf16 (2^-8) modeled at ~1.1e-2 (fail).

typedef _Float16 half2_t __attribute__((ext_vector_type(2)));
typedef _Float16 half4_t __attribute__((ext_vector_type(4)));
typedef _Float16 half8_t __attribute__((ext_vector_type(8)));
typedef float    floatx4 __attribute__((ext_vector_type(4)));

#define SCALE_ 0.125f

__device__ __forceinline__ void async_lds16(const _Float16* g, _Float16* l) {
    __builtin_amdgcn_global_load_lds(
        (const __attribute__((address_space(1))) void*)g,
        (__attribute__((address_space(3))) void*)l,
        16, 0, 0);
}

// ---------------- MFMA GEMM: C[m][n] = sum_k A[m][k] * B[n][k] (+bias[m]) ---
// A: [M][K] f16 k-fast (lda=K). B: [N][K] f16 k-fast (ldb=K). C: [M][N].
// 128x128 tile, BK=32, 4 waves, 16x16x32_f16, global_load_lds width 16.
template <typename OutT>
__global__ __launch_bounds__(256)
void gemm_mfma(const _Float16* __restrict__ A, long aBatch, int K,
               const _Float16* __restrict__ B, long bBatch,
               OutT* __restrict__ C, int ldc, long cBatch,
               const float* __restrict__ bias)
{
    __shared__ _Float16 As[128 * 32];
    __shared__ _Float16 Bs[128 * 32];
    const int tid  = threadIdx.x;
    const int lane = tid & 63;
    const int wave = tid >> 6;
    const int m0 = blockIdx.y * 128;
    const int n0 = blockIdx.x * 128;
    const long bz = blockIdx.z;
    const _Float16* Ag = A + bz * aBatch + (long)m0 * K;
    const _Float16* Bg = B + bz * bBatch + (long)n0 * K;

    // staging map: thread t -> row t>>2 (64 rows/issue), 16B chunk t&3
    const int sr = tid >> 2;
    const int sc = (tid & 3) * 8;

    const int wm = (wave & 1) * 64;
    const int wn = (wave >> 1) * 64;
    const int fm = lane & 15;          // fragment m / n
    const int fk = (lane >> 4) * 8;    // fragment k offset (elems)

    floatx4 acc[4][4];
#pragma unroll
    for (int i = 0; i < 4; ++i)
#pragma unroll
        for (int j = 0; j < 4; ++j) acc[i][j] = (floatx4)0.0f;

    for (int k0 = 0; k0 < K; k0 += 32) {
        __syncthreads();                       // prev iter's ds_reads done
        async_lds16(Ag + (long)sr * K + k0 + sc,        &As[tid * 8]);
        async_lds16(Ag + (long)(sr + 64) * K + k0 + sc, &As[2048 + tid * 8]);
        async_lds16(Bg + (long)sr * K + k0 + sc,        &Bs[tid * 8]);
        async_lds16(Bg + (long)(sr + 64) * K + k0 + sc, &Bs[2048 + tid * 8]);
        __syncthreads();                       // vmcnt(0) drain + barrier

        half8_t a[4], b[4];
#pragma unroll
        for (int i = 0; i < 4; ++i)
            a[i] = *(const half8_t*)&As[(wm + i * 16 + fm) * 32 + fk];
#pragma unroll
        for (int j = 0; j < 4; ++j)
            b[j] = *(const half8_t*)&Bs[(wn + j * 16 + fm) * 32 + fk];
#pragma unroll
        for (int i = 0; i < 4; ++i)
#pragma unroll
            for (int j = 0; j < 4; ++j)
                acc[i][j] = __builtin_amdgcn_mfma_f32_16x16x32_f16(
                    a[i], b[j], acc[i][j], 0, 0, 0);
    }

    // C/D layout: n = lane&15, m = (lane>>4)*4 + reg   [m89/m91-verified]
    const int em = (lane >> 4) * 4;
    const int en = lane & 15;
    OutT* Cb = C + bz * cBatch;
#pragma unroll
    for (int i = 0; i < 4; ++i) {
#pragma unroll
        for (int r = 0; r < 4; ++r) {
            const int m = m0 + wm + i * 16 + em + r;
            const float bi = bias ? bias[m] : 0.0f;
#pragma unroll
            for (int j = 0; j < 4; ++j) {
                const int n = n0 + wn + j * 16 + en;
                Cb[(long)m * ldc + n] = (OutT)(acc[i][j][r] + bi);
            }
        }
    }
}

// ---------------- transpose + fp32->fp16 convert ---------------------------
// src: [R][Cc] fp32 (ld_s). dst: [Cc][R] f16 (ld_d). grid (Cc/64, R/64, batch).
__global__ __launch_bounds__(256)
void transpose_cvt(const float* __restrict__ src, int ld_s, long sB,
                   _Float16* __restrict__ dst, int ld_d, long dB)
{
    __shared__ float tile[64][65];
    const int c0 = blockIdx.x * 64;
    const int r0 = blockIdx.y * 64;
    const float* S = src + (long)blockIdx.z * sB;
    _Float16* D = dst + (long)blockIdx.z * dB;
    const int t = threadIdx.x;
    const int lr = t >> 4;
    const int lc = (t & 15) * 4;
#pragma unroll
    for (int i = 0; i < 4; ++i) {
        const float4 v = *(const float4*)(S + (long)(r0 + lr + 16 * i) * ld_s + c0 + lc);
        tile[lr + 16 * i][lc + 0] = v.x;
        tile[lr + 16 * i][lc + 1] = v.y;
        tile[lr + 16 * i][lc + 2] = v.z;
        tile[lr + 16 * i][lc + 3] = v.w;
    }
    __syncthreads();
    const int rl = (t & 15) * 4;   // dst col base (src row)
    const int cl = t >> 4;         // dst row (src col)
#pragma unroll
    for (int i = 0; i < 4; ++i) {
        const int c = cl + 16 * i;
        half4_t o;
        o[0] = (_Float16)tile[rl + 0][c];
        o[1] = (_Float16)tile[rl + 1][c];
        o[2] = (_Float16)tile[rl + 2][c];
        o[3] = (_Float16)tile[rl + 3][c];
        *(half4_t*)(D + (long)(c0 + c) * ld_d + r0 + rl) = o;
    }
}

// ---------------- wqs[c'][g] = SCALE * w_qkv[c'][g], f16 -------------------
__global__ __launch_bounds__(256)
void scale_wq_kernel(const float* __restrict__ w_qkv, _Float16* __restrict__ wqs)
{
    const int c = blockIdx.x;
    const int t = threadIdx.x;
    const float2 v = *(const float2*)(w_qkv + (long)c * 1536 + t * 2);
    half2_t o;
    o[0] = (_Float16)(v.x * SCALE_);
    o[1] = (_Float16)(v.y * SCALE_);
    *(half2_t*)(wqs + (long)c * 512 + t * 2) = o;
}

// ---------------- softmax over L per (b, f<512) row, f16 in place ----------
__global__ __launch_bounds__(256)
void softmax_rows_h(_Float16* __restrict__ kv)
{
    const int row = blockIdx.x;            // 0..4095
    const int b = row >> 9, f = row & 511;
    _Float16* p = kv + (long)b * 4194304 + (long)f * 4096;
    const int tid = threadIdx.x;

    half8_t h0 = *(const half8_t*)(p + tid * 16);
    half8_t h1 = *(const half8_t*)(p + tid * 16 + 8);
    float v[16];
#pragma unroll
    for (int i = 0; i < 8; ++i) { v[i] = (float)h0[i]; v[8 + i] = (float)h1[i]; }

    float mx = -3.4e38f;
#pragma unroll
    for (int i = 0; i < 16; ++i) mx = fmaxf(mx, v[i]);
#pragma unroll
    for (int off = 32; off > 0; off >>= 1)
        mx = fmaxf(mx, __shfl_down(mx, off));

    __shared__ float red[8];
    if ((tid & 63) == 0) red[tid >> 6] = mx;
    __syncthreads();
    mx = fmaxf(fmaxf(red[0], red[1]), fmaxf(red[2], red[3]));

    float s = 0.0f;
#pragma unroll
    for (int i = 0; i < 16; ++i) { v[i] = __expf(v[i] - mx); s += v[i]; }
#pragma unroll
    for (int off = 32; off > 0; off >>= 1)
        s += __shfl_down(s, off);
    if ((tid & 63) == 0) red[4 + (tid >> 6)] = s;
    __syncthreads();
    const float inv = 1.0f / (red[4] + red[5] + red[6] + red[7]);

#pragma unroll
    for (int i = 0; i < 8; ++i) {
        h0[i] = (_Float16)(v[i] * inv);
        h1[i] = (_Float16)(v[8 + i] * inv);
    }
    *(half8_t*)(p + tid * 16) = h0;
    *(half8_t*)(p + tid * 16 + 8) = h1;
}

// ---------------- context: ctxT[bh][e*64+d] += sum_n k[d,n] v[e,n] ---------
#define NSPLIT 16
__global__ __launch_bounds__(256)
void context_kernel(const _Float16* __restrict__ kv, float* __restrict__ ctxT)
{
    const int bh = blockIdx.x;
    const int b = bh >> 3, h = bh & 7;
    const _Float16* kbase = kv + (long)b * 4194304 + (long)(h * 64) * 4096;
    const _Float16* vbase = kv + (long)b * 4194304 + (long)(512 + h * 64) * 4096;
    const int n0 = blockIdx.y * (4096 / NSPLIT);

    __shared__ float ks[64][65];
    __shared__ float vs[64][65];
    const int tid = threadIdx.x;
    const int tx = tid & 15, ty = tid >> 4;
    const int lr = tid >> 4;
    const int lc = (tid & 15) * 4;

    float acc[4][4] = {};

    for (int nc = 0; nc < 4096 / NSPLIT; nc += 64) {
        __syncthreads();
#pragma unroll
        for (int i = 0; i < 4; ++i) {
            const int r = lr + 16 * i;
            const half4_t kq = *(const half4_t*)(kbase + (long)r * 4096 + n0 + nc + lc);
            const half4_t vq = *(const half4_t*)(vbase + (long)r * 4096 + n0 + nc + lc);
            ks[r][lc] = (float)kq[0]; ks[r][lc + 1] = (float)kq[1];
            ks[r][lc + 2] = (float)kq[2]; ks[r][lc + 3] = (float)kq[3];
            vs[r][lc] = (float)vq[0]; vs[r][lc + 1] = (float)vq[1];
            vs[r][lc + 2] = (float)vq[2]; vs[r][lc + 3] = (float)vq[3];
        }
        __syncthreads();
#pragma unroll 4
        for (int n = 0; n < 64; ++n) {
            float a[4], bv[4];
#pragma unroll
            for (int i = 0; i < 4; ++i) a[i] = ks[ty * 4 + i][n];
#pragma unroll
            for (int j = 0; j < 4; ++j) bv[j] = vs[tx * 4 + j][n];
#pragma unroll
            for (int i = 0; i < 4; ++i)
#pragma unroll
                for (int j = 0; j < 4; ++j)
                    acc[i][j] = fmaf(a[i], bv[j], acc[i][j]);
        }
    }

    float* base = ctxT + (long)bh * 4096;
#pragma unroll
    for (int i = 0; i < 4; ++i)
#pragma unroll
        for (int j = 0; j < 4; ++j)
            atomicAdd(base + (tx * 4 + j) * 64 + (ty * 4 + i), acc[i][j]);
}

// ---- a2tT[b][c][h*64+e... g] = (sum_e ctxT[e][d] w_out[(h,e),c])^T, f16 ----
// output layout [b][c][g], g fast (k-fast A/B operand for the M-build MFMA)
__global__ __launch_bounds__(256)
void a2t_kernel(const float* __restrict__ ctxT, const float* __restrict__ w_out,
                _Float16* __restrict__ a2tT)
{
    const int ct = blockIdx.x, h = blockIdx.y, b = blockIdx.z;
    __shared__ float cs[64][64];      // cs[e][d]
    __shared__ float wsh[64][128];    // wsh[e][c]
    __shared__ _Float16 so[128][64];  // so[c_local][d]
    const int tid = threadIdx.x;
    const float* cbase = ctxT + (long)(b * 8 + h) * 4096;
    {
        const int lr = tid >> 4, lc4 = (tid & 15) * 4;
#pragma unroll
        for (int i = 0; i < 4; ++i) {
            const int e = lr + 16 * i;
            *(float4*)&cs[e][lc4] = *(const float4*)(cbase + e * 64 + lc4);
        }
        const float* wbase = w_out + (long)(h * 64) * 512 + ct * 128;
        const int wr = tid >> 5, wc4 = (tid & 31) * 4;
#pragma unroll
        for (int i = 0; i < 8; ++i) {
            const int e = wr + 8 * i;
            *(float4*)&wsh[e][wc4] = *(const float4*)(wbase + (long)e * 512 + wc4);
        }
    }
    __syncthreads();
    const int tx = tid & 15, ty = tid >> 4;   // c: tx*8+j, d: ty*4+i
    float acc[4][8] = {};
    for (int e = 0; e < 64; ++e) {
        float a[4], bv[8];
#pragma unroll
        for (int i = 0; i < 4; ++i) a[i] = cs[e][ty * 4 + i];
#pragma unroll
        for (int j = 0; j < 8; ++j) bv[j] = wsh[e][tx * 8 + j];
#pragma unroll
        for (int i = 0; i < 4; ++i)
#pragma unroll
            for (int j = 0; j < 8; ++j)
                acc[i][j] = fmaf(a[i], bv[j], acc[i][j]);
    }
#pragma unroll
    for (int i = 0; i < 4; ++i)
#pragma unroll
        for (int j = 0; j < 8; ++j)
            so[tx * 8 + j][ty * 4 + i] = (_Float16)acc[i][j];
    __syncthreads();
    // coalesced f16 write-out: 1024 chunks of 8 halfs
#pragma unroll
    for (int q = tid; q < 1024; q += 256) {
        const int c_local = q >> 3, co = (q & 7) * 8;
        *(half8_t*)(a2tT + (long)b * 262144 + (long)(ct * 128 + c_local) * 512
                    + h * 64 + co) = *(const half8_t*)&so[c_local][co];
    }
}

extern "C" void kernel_launch(void* const* d_in, const int* in_sizes, int n_in,
                              void* d_out, int out_size, void* d_ws, size_t ws_size,
                              hipStream_t stream)
{
    const float* x      = (const float*)d_in[0];   // (8,512,4096)
    const float* w_qkv  = (const float*)d_in[1];   // (512,1536)
    const float* w_out  = (const float*)d_in[2];   // (512,512)
    const float* b_out  = (const float*)d_in[3];   // (512,)
    float* out = (float*)d_out;                    // (8,512,4096)

    char* wsb = (char*)d_ws;                       // ~107 MB total
    _Float16* kv   = (_Float16*)(wsb);             // 64 MB  [b][f][l]
    _Float16* xT   = (_Float16*)(wsb + 67108864);  // 32 MB  [b][l][c]
    _Float16* wkvT = (_Float16*)(wsb + 100663296); // 1 MB   [f][c]
    _Float16* wqs  = (_Float16*)(wsb + 101711872); // 0.5 MB [c'][g]
    _Float16* a2tT = (_Float16*)(wsb + 102236160); // 4 MB   [b][c][g]
    _Float16* mf   = (_Float16*)(wsb + 106430464); // 4 MB   [b][c][c']
    float*    ctxT = (float*)   (wsb + 110624768); // 1 MB   [bh][e*64+d]

    // xT = transpose+cvt(x): src rows c=512, cols l=4096
    transpose_cvt<<<dim3(64, 8, 8), 256, 0, stream>>>(
        x, 4096, 2097152L, xT, 512, 2097152L);
    // wkvT[f][c]: src rows c=512 (ld 1536, offset 512), cols f=1024
    transpose_cvt<<<dim3(16, 8, 1), 256, 0, stream>>>(
        w_qkv + 512, 1536, 0L, wkvT, 512, 0L);
    // wqs[c'][g] = SCALE * w_qkv[c'][g]
    scale_wq_kernel<<<dim3(512), 256, 0, stream>>>(w_qkv, wqs);

    // K1: kv[b][f][l] = sum_c wkvT[f][c] * xT[b][l][c]
    gemm_mfma<_Float16><<<dim3(32, 8, 8), 256, 0, stream>>>(
        wkvT, 0L, 512, xT, 2097152L, kv, 4096, 4194304L, nullptr);

    // K2: softmax over L on the k half
    softmax_rows_h<<<dim3(4096), 256, 0, stream>>>(kv);

    // K3: context (fp32 accumulate via atomics)
    hipMemsetAsync(ctxT, 0, 262144 * sizeof(float), stream);
    context_kernel<<<dim3(64, NSPLIT), 256, 0, stream>>>(kv, ctxT);

    // K4a: a2tT
    a2t_kernel<<<dim3(4, 8, 8), 256, 0, stream>>>(ctxT, w_out, a2tT);

    // K4m: mf[b][c][c'] = sum_g a2tT[b][c][g] * wqs[c'][g]   (= M^T, f16)
    gemm_mfma<_Float16><<<dim3(4, 4, 8), 256, 0, stream>>>(
        a2tT, 262144L, 512, wqs, 0L, mf, 512, 262144L, nullptr);

    // K5: out[b][c][l] = sum_c' mf[b][c][c'] * xT[b][l][c'] + b_out[c]
    gemm_mfma<float><<<dim3(32, 4, 8), 256, 0, stream>>>(
        mf, 262144L, 512, xT, 2097152L, out, 4096, 2097152L, b_out);
}

// Round 3
// 281.289 us; speedup vs baseline: 3.0791x; 1.2035x over previous
//
#include <hip/hip_runtime.h>

// LinearAttention, fp16-MFMA restructuring (round 3).
//   xT   = transpose+cvt(x)          [b][l][c] f16   (B-operand for K1,K5)
//   kv   = wkvT @ xT^T  (MFMA)       [b][f][l] f16, f<512:k, f>=512:v
//   k    = softmax_L(k)              in place, f16
//   ctxP = v k^T partials (MFMA, K split 16)  [s][bh][e*64+d] f32
//   a2tT = (sum_s ctxP . w_out)^T    [b][c][g] f16  (k-fast for M-build)
//   Mf   = a2tT @ wqs^T (MFMA)       [b][c][c'] f16 = A-operand of K5
//   out  = Mf @ xT^T + b_out (MFMA, fp32 out)
// q never materialized (linear in x, folded into Mf).
// Round-3 change: context_kernel (84 us, MfmaUtil=0, 4.2M atomics) replaced
// by MFMA batched GEMM with K-split partials; a2t absorbs the reduction.

typedef _Float16 half2_t __attribute__((ext_vector_type(2)));
typedef _Float16 half4_t __attribute__((ext_vector_type(4)));
typedef _Float16 half8_t __attribute__((ext_vector_type(8)));
typedef float    floatx4 __attribute__((ext_vector_type(4)));

#define SCALE_ 0.125f
#define CSPLIT 16

__device__ __forceinline__ void async_lds16(const _Float16* g, _Float16* l) {
    __builtin_amdgcn_global_load_lds(
        (const __attribute__((address_space(1))) void*)g,
        (__attribute__((address_space(3))) void*)l,
        16, 0, 0);
}

// ---------------- MFMA GEMM: C[m][n] = sum_k A[m][k] * B[n][k] (+bias[m]) ---
// A: [M][K] f16 k-fast (lda=K). B: [N][K] f16 k-fast (ldb=K). C: [M][N].
// 128x128 tile, BK=32, 4 waves, 16x16x32_f16, global_load_lds width 16.
template <typename OutT>
__global__ __launch_bounds__(256)
void gemm_mfma(const _Float16* __restrict__ A, long aBatch, int K,
               const _Float16* __restrict__ B, long bBatch,
               OutT* __restrict__ C, int ldc, long cBatch,
               const float* __restrict__ bias)
{
    __shared__ _Float16 As[128 * 32];
    __shared__ _Float16 Bs[128 * 32];
    const int tid  = threadIdx.x;
    const int lane = tid & 63;
    const int wave = tid >> 6;
    const int m0 = blockIdx.y * 128;
    const int n0 = blockIdx.x * 128;
    const long bz = blockIdx.z;
    const _Float16* Ag = A + bz * aBatch + (long)m0 * K;
    const _Float16* Bg = B + bz * bBatch + (long)n0 * K;

    // staging map: thread t -> row t>>2 (64 rows/issue), 16B chunk t&3
    const int sr = tid >> 2;
    const int sc = (tid & 3) * 8;

    const int wm = (wave & 1) * 64;
    const int wn = (wave >> 1) * 64;
    const int fm = lane & 15;          // fragment m / n
    const int fk = (lane >> 4) * 8;    // fragment k offset (elems)

    floatx4 acc[4][4];
#pragma unroll
    for (int i = 0; i < 4; ++i)
#pragma unroll
        for (int j = 0; j < 4; ++j) acc[i][j] = (floatx4)0.0f;

    for (int k0 = 0; k0 < K; k0 += 32) {
        __syncthreads();                       // prev iter's ds_reads done
        async_lds16(Ag + (long)sr * K + k0 + sc,        &As[tid * 8]);
        async_lds16(Ag + (long)(sr + 64) * K + k0 + sc, &As[2048 + tid * 8]);
        async_lds16(Bg + (long)sr * K + k0 + sc,        &Bs[tid * 8]);
        async_lds16(Bg + (long)(sr + 64) * K + k0 + sc, &Bs[2048 + tid * 8]);
        __syncthreads();                       // vmcnt(0) drain + barrier

        half8_t a[4], b[4];
#pragma unroll
        for (int i = 0; i < 4; ++i)
            a[i] = *(const half8_t*)&As[(wm + i * 16 + fm) * 32 + fk];
#pragma unroll
        for (int j = 0; j < 4; ++j)
            b[j] = *(const half8_t*)&Bs[(wn + j * 16 + fm) * 32 + fk];
#pragma unroll
        for (int i = 0; i < 4; ++i)
#pragma unroll
            for (int j = 0; j < 4; ++j)
                acc[i][j] = __builtin_amdgcn_mfma_f32_16x16x32_f16(
                    a[i], b[j], acc[i][j], 0, 0, 0);
    }

    // C/D layout: n = lane&15, m = (lane>>4)*4 + reg   [m89/m91-verified]
    const int em = (lane >> 4) * 4;
    const int en = lane & 15;
    OutT* Cb = C + bz * cBatch;
#pragma unroll
    for (int i = 0; i < 4; ++i) {
#pragma unroll
        for (int r = 0; r < 4; ++r) {
            const int m = m0 + wm + i * 16 + em + r;
            const float bi = bias ? bias[m] : 0.0f;
#pragma unroll
            for (int j = 0; j < 4; ++j) {
                const int n = n0 + wn + j * 16 + en;
                Cb[(long)m * ldc + n] = (OutT)(acc[i][j][r] + bi);
            }
        }
    }
}

// ---------------- context via MFMA: ctxP[s][bh][e*64+d] --------------------
// Per (bh, slab s): C[m=e][n=d] = sum_l v[e,l] k[d,l] over slab's 256 l's.
// A = v rows (l-fast), B = k rows (l-fast) -> zero repacking.
__global__ __launch_bounds__(256)
void context_mfma(const _Float16* __restrict__ kv, float* __restrict__ ctxP)
{
    const int bh = blockIdx.y;             // 0..63
    const int b = bh >> 3, h = bh & 7;
    const int l0 = blockIdx.x * (4096 / CSPLIT);   // 256-wide l slab
    const _Float16* vbase = kv + (long)b * 4194304 + (long)(512 + h * 64) * 4096;
    const _Float16* kbase = kv + (long)b * 4194304 + (long)(h * 64) * 4096;

    __shared__ _Float16 As[64 * 32];   // v tile [e][32]
    __shared__ _Float16 Bs[64 * 32];   // k tile [d][32]
    const int tid  = threadIdx.x;
    const int lane = tid & 63;
    const int wave = tid >> 6;
    const int sr = tid >> 2;           // 0..63
    const int sc = (tid & 3) * 8;
    const int wm = (wave & 1) * 32;
    const int wn = (wave >> 1) * 32;
    const int fm = lane & 15;
    const int fk = (lane >> 4) * 8;

    floatx4 acc[2][2];
#pragma unroll
    for (int i = 0; i < 2; ++i)
#pragma unroll
        for (int j = 0; j < 2; ++j) acc[i][j] = (floatx4)0.0f;

    for (int k0 = 0; k0 < 4096 / CSPLIT; k0 += 32) {
        __syncthreads();
        async_lds16(vbase + (long)sr * 4096 + l0 + k0 + sc, &As[tid * 8]);
        async_lds16(kbase + (long)sr * 4096 + l0 + k0 + sc, &Bs[tid * 8]);
        __syncthreads();

        half8_t a[2], b2[2];
#pragma unroll
        for (int i = 0; i < 2; ++i)
            a[i] = *(const half8_t*)&As[(wm + i * 16 + fm) * 32 + fk];
#pragma unroll
        for (int j = 0; j < 2; ++j)
            b2[j] = *(const half8_t*)&Bs[(wn + j * 16 + fm) * 32 + fk];
#pragma unroll
        for (int i = 0; i < 2; ++i)
#pragma unroll
            for (int j = 0; j < 2; ++j)
                acc[i][j] = __builtin_amdgcn_mfma_f32_16x16x32_f16(
                    a[i], b2[j], acc[i][j], 0, 0, 0);
    }

    const int em = (lane >> 4) * 4;
    const int en = lane & 15;
    float* base = ctxP + ((long)blockIdx.x * 64 + bh) * 4096;
#pragma unroll
    for (int i = 0; i < 2; ++i)
#pragma unroll
        for (int r = 0; r < 4; ++r)
#pragma unroll
            for (int j = 0; j < 2; ++j)
                base[(wm + i * 16 + em + r) * 64 + wn + j * 16 + en] = acc[i][j][r];
}

// ---------------- transpose + fp32->fp16 convert ---------------------------
// src: [R][Cc] fp32 (ld_s). dst: [Cc][R] f16 (ld_d). grid (Cc/64, R/64, batch).
__global__ __launch_bounds__(256)
void transpose_cvt(const float* __restrict__ src, int ld_s, long sB,
                   _Float16* __restrict__ dst, int ld_d, long dB)
{
    __shared__ float tile[64][65];
    const int c0 = blockIdx.x * 64;
    const int r0 = blockIdx.y * 64;
    const float* S = src + (long)blockIdx.z * sB;
    _Float16* D = dst + (long)blockIdx.z * dB;
    const int t = threadIdx.x;
    const int lr = t >> 4;
    const int lc = (t & 15) * 4;
#pragma unroll
    for (int i = 0; i < 4; ++i) {
        const float4 v = *(const float4*)(S + (long)(r0 + lr + 16 * i) * ld_s + c0 + lc);
        tile[lr + 16 * i][lc + 0] = v.x;
        tile[lr + 16 * i][lc + 1] = v.y;
        tile[lr + 16 * i][lc + 2] = v.z;
        tile[lr + 16 * i][lc + 3] = v.w;
    }
    __syncthreads();
    const int rl = (t & 15) * 4;   // dst col base (src row)
    const int cl = t >> 4;         // dst row (src col)
#pragma unroll
    for (int i = 0; i < 4; ++i) {
        const int c = cl + 16 * i;
        half4_t o;
        o[0] = (_Float16)tile[rl + 0][c];
        o[1] = (_Float16)tile[rl + 1][c];
        o[2] = (_Float16)tile[rl + 2][c];
        o[3] = (_Float16)tile[rl + 3][c];
        *(half4_t*)(D + (long)(c0 + c) * ld_d + r0 + rl) = o;
    }
}

// ---------------- wqs[c'][g] = SCALE * w_qkv[c'][g], f16 -------------------
__global__ __launch_bounds__(256)
void scale_wq_kernel(const float* __restrict__ w_qkv, _Float16* __restrict__ wqs)
{
    const int c = blockIdx.x;
    const int t = threadIdx.x;
    const float2 v = *(const float2*)(w_qkv + (long)c * 1536 + t * 2);
    half2_t o;
    o[0] = (_Float16)(v.x * SCALE_);
    o[1] = (_Float16)(v.y * SCALE_);
    *(half2_t*)(wqs + (long)c * 512 + t * 2) = o;
}

// ---------------- softmax over L per (b, f<512) row, f16 in place ----------
__global__ __launch_bounds__(256)
void softmax_rows_h(_Float16* __restrict__ kv)
{
    const int row = blockIdx.x;            // 0..4095
    const int b = row >> 9, f = row & 511;
    _Float16* p = kv + (long)b * 4194304 + (long)f * 4096;
    const int tid = threadIdx.x;

    half8_t h0 = *(const half8_t*)(p + tid * 16);
    half8_t h1 = *(const half8_t*)(p + tid * 16 + 8);
    float v[16];
#pragma unroll
    for (int i = 0; i < 8; ++i) { v[i] = (float)h0[i]; v[8 + i] = (float)h1[i]; }

    float mx = -3.4e38f;
#pragma unroll
    for (int i = 0; i < 16; ++i) mx = fmaxf(mx, v[i]);
#pragma unroll
    for (int off = 32; off > 0; off >>= 1)
        mx = fmaxf(mx, __shfl_down(mx, off));

    __shared__ float red[8];
    if ((tid & 63) == 0) red[tid >> 6] = mx;
    __syncthreads();
    mx = fmaxf(fmaxf(red[0], red[1]), fmaxf(red[2], red[3]));

    float s = 0.0f;
#pragma unroll
    for (int i = 0; i < 16; ++i) { v[i] = __expf(v[i] - mx); s += v[i]; }
#pragma unroll
    for (int off = 32; off > 0; off >>= 1)
        s += __shfl_down(s, off);
    if ((tid & 63) == 0) red[4 + (tid >> 6)] = s;
    __syncthreads();
    const float inv = 1.0f / (red[4] + red[5] + red[6] + red[7]);

#pragma unroll
    for (int i = 0; i < 8; ++i) {
        h0[i] = (_Float16)(v[i] * inv);
        h1[i] = (_Float16)(v[8 + i] * inv);
    }
    *(half8_t*)(p + tid * 16) = h0;
    *(half8_t*)(p + tid * 16 + 8) = h1;
}

// ---- a2tT[b][c][g] = (sum_e (sum_s ctxP)[e][d] w_out[(h,e),c])^T, f16 -----
// output layout [b][c][g], g fast (k-fast A/B operand for the M-build MFMA)
__global__ __launch_bounds__(256)
void a2t_kernel(const float* __restrict__ ctxP, const float* __restrict__ w_out,
                _Float16* __restrict__ a2tT)
{
    const int ct = blockIdx.x, h = blockIdx.y, b = blockIdx.z;
    __shared__ float cs[64][64];      // cs[e][d]
    __shared__ float wsh[64][128];    // wsh[e][c]
    __shared__ _Float16 so[128][64];  // so[c_local][d]
    const int tid = threadIdx.x;
    {
        const int lr = tid >> 4, lc4 = (tid & 15) * 4;
        floatx4 accv[4];
#pragma unroll
        for (int i = 0; i < 4; ++i) accv[i] = (floatx4)0.0f;
        for (int s = 0; s < CSPLIT; ++s) {
            const float* cbase = ctxP + ((long)s * 64 + b * 8 + h) * 4096;
#pragma unroll
            for (int i = 0; i < 4; ++i)
                accv[i] += *(const floatx4*)(cbase + (lr + 16 * i) * 64 + lc4);
        }
#pragma unroll
        for (int i = 0; i < 4; ++i)
            *(floatx4*)&cs[lr + 16 * i][lc4] = accv[i];

        const float* wbase = w_out + (long)(h * 64) * 512 + ct * 128;
        const int wr = tid >> 5, wc4 = (tid & 31) * 4;
#pragma unroll
        for (int i = 0; i < 8; ++i) {
            const int e = wr + 8 * i;
            *(float4*)&wsh[e][wc4] = *(const float4*)(wbase + (long)e * 512 + wc4);
        }
    }
    __syncthreads();
    const int tx = tid & 15, ty = tid >> 4;   // c: tx*8+j, d: ty*4+i
    float acc[4][8] = {};
    for (int e = 0; e < 64; ++e) {
        float a[4], bv[8];
#pragma unroll
        for (int i = 0; i < 4; ++i) a[i] = cs[e][ty * 4 + i];
#pragma unroll
        for (int j = 0; j < 8; ++j) bv[j] = wsh[e][tx * 8 + j];
#pragma unroll
        for (int i = 0; i < 4; ++i)
#pragma unroll
            for (int j = 0; j < 8; ++j)
                acc[i][j] = fmaf(a[i], bv[j], acc[i][j]);
    }
#pragma unroll
    for (int i = 0; i < 4; ++i)
#pragma unroll
        for (int j = 0; j < 8; ++j)
            so[tx * 8 + j][ty * 4 + i] = (_Float16)acc[i][j];
    __syncthreads();
    // coalesced f16 write-out: 1024 chunks of 8 halfs
#pragma unroll
    for (int q = tid; q < 1024; q += 256) {
        const int c_local = q >> 3, co = (q & 7) * 8;
        *(half8_t*)(a2tT + (long)b * 262144 + (long)(ct * 128 + c_local) * 512
                    + h * 64 + co) = *(const half8_t*)&so[c_local][co];
    }
}

extern "C" void kernel_launch(void* const* d_in, const int* in_sizes, int n_in,
                              void* d_out, int out_size, void* d_ws, size_t ws_size,
                              hipStream_t stream)
{
    const float* x      = (const float*)d_in[0];   // (8,512,4096)
    const float* w_qkv  = (const float*)d_in[1];   // (512,1536)
    const float* w_out  = (const float*)d_in[2];   // (512,512)
    const float* b_out  = (const float*)d_in[3];   // (512,)
    float* out = (float*)d_out;                    // (8,512,4096)

    char* wsb = (char*)d_ws;                       // ~122 MB total
    _Float16* kv   = (_Float16*)(wsb);             // 64 MB  [b][f][l]
    _Float16* xT   = (_Float16*)(wsb + 67108864);  // 32 MB  [b][l][c]
    _Float16* wkvT = (_Float16*)(wsb + 100663296); // 1 MB   [f][c]
    _Float16* wqs  = (_Float16*)(wsb + 101711872); // 0.5 MB [c'][g]
    _Float16* a2tT = (_Float16*)(wsb + 102236160); // 4 MB   [b][c][g]
    _Float16* mf   = (_Float16*)(wsb + 106430464); // 4 MB   [b][c][c']
    float*    ctxP = (float*)   (wsb + 110624768); // 16 MB  [s][bh][e*64+d]

    // xT = transpose+cvt(x): src rows c=512, cols l=4096
    transpose_cvt<<<dim3(64, 8, 8), 256, 0, stream>>>(
        x, 4096, 2097152L, xT, 512, 2097152L);
    // wkvT[f][c]: src rows c=512 (ld 1536, offset 512), cols f=1024
    transpose_cvt<<<dim3(16, 8, 1), 256, 0, stream>>>(
        w_qkv + 512, 1536, 0L, wkvT, 512, 0L);
    // wqs[c'][g] = SCALE * w_qkv[c'][g]
    scale_wq_kernel<<<dim3(512), 256, 0, stream>>>(w_qkv, wqs);

    // K1: kv[b][f][l] = sum_c wkvT[f][c] * xT[b][l][c]
    gemm_mfma<_Float16><<<dim3(32, 8, 8), 256, 0, stream>>>(
        wkvT, 0L, 512, xT, 2097152L, kv, 4096, 4194304L, nullptr);

    // K2: softmax over L on the k half
    softmax_rows_h<<<dim3(4096), 256, 0, stream>>>(kv);

    // K3: context partials via MFMA (no atomics, no memset)
    context_mfma<<<dim3(CSPLIT, 64), 256, 0, stream>>>(kv, ctxP);

    // K4a: a2tT (reduces the CSPLIT partials on load)
    a2t_kernel<<<dim3(4, 8, 8), 256, 0, stream>>>(ctxP, w_out, a2tT);

    // K4m: mf[b][c][c'] = sum_g a2tT[b][c][g] * wqs[c'][g]   (= M^T, f16)
    gemm_mfma<_Float16><<<dim3(4, 4, 8), 256, 0, stream>>>(
        a2tT, 262144L, 512, wqs, 0L, mf, 512, 262144L, nullptr);

    // K5: out[b][c][l] = sum_c' mf[b][c][c'] * xT[b][l][c'] + b_out[c]
    gemm_mfma<float><<<dim3(32, 4, 8), 256, 0, stream>>>(
        mf, 262144L, 512, xT, 2097152L, out, 4096, 2097152L, b_out);
}